// Round 5
// baseline (477.793 us; speedup 1.0000x reference)
//
#include <hip/hip_runtime.h>

// MHConvAttention MFMA v5. B=16, C=256, H=W=64, NH=8, hd=32, WS=5.
// v5 = v4 with content_combine halo-stage index fix (hp=idx>>2, gg=idx&3).
//
// Workspace layout (bytes), total 136,462,336:
//   [0)           qkv bf16 (65536,768)  100,663,296   ALIASED with:
//   [0)           xpad bf16 (16,66,66,256) 35,684,352 (dead after conv)
//   [100663296)   x / result bf16 (65536,256) 33,554,432
//   [134217728)   cl f32 (128,32,32)        524,288
//   [134742016)   S  f32 (128,32)            16,384
//   [134758400)   wrb bf16 (9,256,256)    1,179,648
//   [135938048)   wq  bf16 (768,256)        393,216
//   [136331264)   wo  bf16 (256,256)        131,072

typedef unsigned short u16;
typedef __bf16 bf16x8 __attribute__((ext_vector_type(8)));
typedef float f32x4 __attribute__((ext_vector_type(4)));
#define HW 4096

__device__ __forceinline__ float bf2f(u16 u){
  unsigned v = ((unsigned)u) << 16;
  return __builtin_bit_cast(float, v);
}
__device__ __forceinline__ u16 f2bf(float f){
  unsigned u = __builtin_bit_cast(unsigned, f);
  u = u + 0x7fffu + ((u >> 16) & 1u);   // RNE
  return (u16)(u >> 16);
}
__device__ __forceinline__ unsigned pack2(float a, float b){
  return (unsigned)f2bf(a) | ((unsigned)f2bf(b) << 16);
}
__device__ __forceinline__ void unpack2(unsigned u, float& a, float& b){
  a = bf2f((u16)(u & 0xffffu)); b = bf2f((u16)(u >> 16));
}
__device__ __forceinline__ void unp8(uint4 r, float* v){
  unpack2(r.x, v[0], v[1]); unpack2(r.y, v[2], v[3]);
  unpack2(r.z, v[4], v[5]); unpack2(r.w, v[6], v[7]);
}
__device__ __forceinline__ int swz(int p){ return (p&3) ^ ((p>>2)&3); }

__device__ __forceinline__ void gl2lds16(const u16* g, u16* l){
  __builtin_amdgcn_global_load_lds((__attribute__((address_space(1))) void*)g,
                                   (__attribute__((address_space(3))) void*)l, 16, 0, 0);
}

// ---------------- zero only the 1-px border of xpad ----------------
__global__ void zero_border(u16* __restrict__ xpad){
  int idx = blockIdx.x*256 + threadIdx.x;
  int g = idx & 31;
  int p = idx >> 5;
  int b = p / 260; int r = p - b*260;
  int y, x;
  if (r < 66)      { y = 0;      x = r; }
  else if (r < 132){ y = 65;     x = r-66; }
  else if (r < 196){ y = r-131;  x = 0; }
  else             { y = r-195;  x = 65; }
  *(uint4*)&xpad[((size_t)b*4356 + (size_t)y*66 + x)*256 + g*8] = uint4{0,0,0,0};
}

// ---------------- src NCHW f32 -> xpad NHWC bf16 (66x66, interior) ----------------
__global__ __launch_bounds__(256) void to_nhwc(const float* __restrict__ src,
                                               u16* __restrict__ xpad){
  __shared__ u16 sl[64*264];
  const int t = threadIdx.x, w = t>>6, lane = t&63;
  const int y = blockIdx.x, b = blockIdx.y;
  for (int cc = 0; cc < 64; ++cc){
    const int c = cc*4 + w;
    float v = src[((size_t)(b*256 + c))*HW + y*64 + lane];
    sl[lane*264 + c] = f2bf(v);
  }
  __syncthreads();
  #pragma unroll
  for (int i = 0; i < 8; ++i){
    int idx = t + 256*i;
    int p = idx >> 5, g = idx & 31;
    uint4 v = *(const uint4*)&sl[p*264 + g*8];
    *(uint4*)&xpad[((size_t)b*4356 + (size_t)(y+1)*66 + (p+1))*256 + g*8] = v;
  }
}

// ---------------- repack all weights to bf16 ----------------
__global__ void repack_w(const float* __restrict__ cpe_w, const float* __restrict__ qkv_w,
                         const float* __restrict__ out_w, u16* __restrict__ wrb,
                         u16* __restrict__ wq, u16* __restrict__ wo){
  int idx = blockIdx.x*256 + threadIdx.x;
  if (idx < 589824){
    int kk = idx >> 16, o = (idx >> 8) & 255, c = idx & 255;
    wrb[idx] = f2bf(cpe_w[((o*256 + c)*9) + kk]);
  } else if (idx < 786432){
    int j = idx - 589824;
    wq[j] = f2bf(qkv_w[j]);
  } else {
    int j = idx - 786432;
    wo[j] = f2bf(out_w[j]);
  }
}

// ---------------- CPE 3x3 conv: implicit GEMM, swapped-operand MFMA ----------------
__global__ __launch_bounds__(256) void conv_mfma(const u16* __restrict__ xpad,
    const u16* __restrict__ wrb, const float* __restrict__ bias,
    u16* __restrict__ xout){
  __shared__ u16 As[4096];
  __shared__ u16 Bs[4096];
  const int t = threadIdx.x, w = t>>6, lane = t&63;
  const int idx = blockIdx.x;
  const int x8 = idx&7, q = idx>>3;
  const int ot = q & 1, nb = (q>>1)*8 + x8;
  const int pg = nb*128;
  const int b = pg>>12, hw0 = pg&4095, y0 = hw0>>6;
  const int o0 = ot*128;
  const size_t xb = (size_t)b*4356;
  const int sp = t>>2;
  const int cs = (t&3) ^ swz(sp);
  const u16* agp0 = xpad + (xb + (size_t)(y0+1)*66 + sp + 1)*256 + cs*8;
  const u16* agp1 = agp0 + 66*256;
  const u16* bgp0 = wrb + (size_t)(o0 + sp)*256 + cs*8;
  const u16* bgp1 = bgp0 + 64*256;
  const int wm = w&1, wn = w>>1;
  int a_off[4], b_off[4];
  #pragma unroll
  for (int i = 0; i < 4; ++i){
    int p = wm*64 + i*16 + (lane&15);
    a_off[i] = p*32 + ((((lane>>4) ^ swz(p)) & 3) << 3);
    int r = wn*64 + i*16 + (lane&15);
    b_off[i] = r*32 + ((((lane>>4) ^ swz(r)) & 3) << 3);
  }
  f32x4 acc[4][4];
  #pragma unroll
  for (int i=0;i<4;++i)
    #pragma unroll
    for (int j=0;j<4;++j) acc[i][j] = f32x4{0.f,0.f,0.f,0.f};

  for (int c0 = 0; c0 < 256; c0 += 32){
    for (int kk = 0; kk < 9; ++kk){
      const int toff = ((kk/3 - 1)*66 + (kk%3 - 1))*256;
      __syncthreads();
      gl2lds16(agp0 + toff + c0, &As[t*8]);
      gl2lds16(agp1 + toff + c0, &As[2048 + t*8]);
      gl2lds16(bgp0 + kk*65536 + c0, &Bs[t*8]);
      gl2lds16(bgp1 + kk*65536 + c0, &Bs[2048 + t*8]);
      __syncthreads();
      bf16x8 af[4], bfr[4];
      #pragma unroll
      for (int i = 0; i < 4; ++i){
        af[i]  = __builtin_bit_cast(bf16x8, *(const uint4*)&As[a_off[i]]);
        bfr[i] = __builtin_bit_cast(bf16x8, *(const uint4*)&Bs[b_off[i]]);
      }
      #pragma unroll
      for (int mt = 0; mt < 4; ++mt)
        #pragma unroll
        for (int nt = 0; nt < 4; ++nt)
          acc[mt][nt] = __builtin_amdgcn_mfma_f32_16x16x32_bf16(bfr[nt], af[mt], acc[mt][nt], 0,0,0);
    }
  }
  #pragma unroll
  for (int nt = 0; nt < 4; ++nt){
    const int och4 = o0 + wn*64 + nt*16 + (lane>>4)*4;
    float4 b4 = *(const float4*)&bias[och4];
    #pragma unroll
    for (int mt = 0; mt < 4; ++mt){
      const int px = wm*64 + mt*16 + (lane&15);
      const int hw = hw0 + px;
      const int y = hw>>6, x = hw&63;
      ushort4 r4 = *(const ushort4*)&xpad[(xb + (size_t)(y+1)*66 + x + 1)*256 + och4];
      ushort4 s;
      s.x = f2bf(acc[mt][nt][0] + b4.x + bf2f(r4.x));
      s.y = f2bf(acc[mt][nt][1] + b4.y + bf2f(r4.y));
      s.z = f2bf(acc[mt][nt][2] + b4.z + bf2f(r4.z));
      s.w = f2bf(acc[mt][nt][3] + b4.w + bf2f(r4.w));
      *(ushort4*)&xout[(size_t)(pg + px)*256 + och4] = s;
    }
  }
}

// ---------------- K=256 MFMA GEMM ----------------
template<int NO, int NOT, bool F32OUT>
__global__ __launch_bounds__(256) void gemm_mfma(const u16* __restrict__ act,
    const u16* __restrict__ wt, const float* __restrict__ bias, void* __restrict__ out){
  __shared__ u16 As[4096];
  __shared__ u16 Bs[4096];
  const int t = threadIdx.x, w = t>>6, lane = t&63;
  const int idx = blockIdx.x;
  const int x8 = idx&7, q = idx>>3;
  const int ot = q % NOT, nb = (q / NOT)*8 + x8;
  const int pg = nb*128, o0 = ot*128;
  const int sp = t>>2;
  const int cs = (t&3) ^ swz(sp);
  const u16* agp0 = act + (size_t)(pg + sp)*256 + cs*8;
  const u16* agp1 = agp0 + 64*256;
  const u16* bgp0 = wt + (size_t)(o0 + sp)*256 + cs*8;
  const u16* bgp1 = bgp0 + 64*256;
  const int wm = w&1, wn = w>>1;
  int a_off[4], b_off[4];
  #pragma unroll
  for (int i = 0; i < 4; ++i){
    int p = wm*64 + i*16 + (lane&15);
    a_off[i] = p*32 + ((((lane>>4) ^ swz(p)) & 3) << 3);
    int r = wn*64 + i*16 + (lane&15);
    b_off[i] = r*32 + ((((lane>>4) ^ swz(r)) & 3) << 3);
  }
  f32x4 acc[4][4];
  #pragma unroll
  for (int i=0;i<4;++i)
    #pragma unroll
    for (int j=0;j<4;++j) acc[i][j] = f32x4{0.f,0.f,0.f,0.f};

  for (int c0 = 0; c0 < 256; c0 += 32){
    __syncthreads();
    gl2lds16(agp0 + c0, &As[t*8]);
    gl2lds16(agp1 + c0, &As[2048 + t*8]);
    gl2lds16(bgp0 + c0, &Bs[t*8]);
    gl2lds16(bgp1 + c0, &Bs[2048 + t*8]);
    __syncthreads();
    bf16x8 af[4], bfr[4];
    #pragma unroll
    for (int i = 0; i < 4; ++i){
      af[i]  = __builtin_bit_cast(bf16x8, *(const uint4*)&As[a_off[i]]);
      bfr[i] = __builtin_bit_cast(bf16x8, *(const uint4*)&Bs[b_off[i]]);
    }
    #pragma unroll
    for (int mt = 0; mt < 4; ++mt)
      #pragma unroll
      for (int nt = 0; nt < 4; ++nt){
        if constexpr (F32OUT)
          acc[mt][nt] = __builtin_amdgcn_mfma_f32_16x16x32_bf16(af[mt], bfr[nt], acc[mt][nt], 0,0,0);
        else
          acc[mt][nt] = __builtin_amdgcn_mfma_f32_16x16x32_bf16(bfr[nt], af[mt], acc[mt][nt], 0,0,0);
      }
  }
  if constexpr (F32OUT){
    const int col = lane&15, row_l = (lane>>4)*4;
    const int b = pg>>12, hw0 = pg&4095;
    float* op = (float*)out;
    #pragma unroll
    for (int nt = 0; nt < 4; ++nt){
      const int och = o0 + wn*64 + nt*16 + col;
      const float bo = bias[och];
      #pragma unroll
      for (int mt = 0; mt < 4; ++mt){
        const int pl = wm*64 + mt*16 + row_l;
        float4 v;
        v.x = acc[mt][nt][0]+bo; v.y = acc[mt][nt][1]+bo;
        v.z = acc[mt][nt][2]+bo; v.w = acc[mt][nt][3]+bo;
        *(float4*)&op[((size_t)b*256 + och)*HW + hw0 + pl] = v;
      }
    }
  } else {
    u16* op = (u16*)out;
    #pragma unroll
    for (int nt = 0; nt < 4; ++nt){
      const int och4 = o0 + wn*64 + nt*16 + (lane>>4)*4;
      #pragma unroll
      for (int mt = 0; mt < 4; ++mt){
        const int px = wm*64 + mt*16 + (lane&15);
        ushort4 s;
        s.x = f2bf(acc[mt][nt][0]); s.y = f2bf(acc[mt][nt][1]);
        s.z = f2bf(acc[mt][nt][2]); s.w = f2bf(acc[mt][nt][3]);
        *(ushort4*)&op[(size_t)(pg + px)*NO + och4] = s;
      }
    }
  }
}

__global__ void zero_cl(float* __restrict__ cl){
  cl[blockIdx.x*256 + threadIdx.x] = 0.f;   // zeros cl (131072) + S (4096)
}

// ---------------- lambda: cl'[b',i,o] = sum_n exp(k[n][i])*v[n][o]; S[b',i] = sum exp ----
__global__ __launch_bounds__(64) void lambda_kern(const u16* __restrict__ qkv,
                                                  float* __restrict__ cl,
                                                  float* __restrict__ S){
  __shared__ float Kl[64*36];
  __shared__ float Vl[64*36];
  const int t = threadIdx.x;
  const int bp = blockIdx.x, split = blockIdx.y;   // 16 splits
  const int b = bp>>3, h = bp&7;
  const int ig = t&7, og = t>>3;
  float acc[4][4];
  float sacc[4] = {0.f,0.f,0.f,0.f};
  #pragma unroll
  for (int i=0;i<4;++i)
    #pragma unroll
    for (int j=0;j<4;++j) acc[i][j] = 0.f;
  for (int chunk = 0; chunk < 4; ++chunk){
    const int n = split*256 + chunk*64 + t;
    const u16* kp = qkv + (size_t)(b*HW + n)*768 + 256 + h*32;
    const u16* vp = kp + 256;
    uint4 k4[4], v4[4];
    #pragma unroll
    for (int qq=0;qq<4;++qq){ k4[qq] = ((const uint4*)kp)[qq]; v4[qq] = ((const uint4*)vp)[qq]; }
    __syncthreads();
    #pragma unroll
    for (int qq=0;qq<4;++qq){
      float kv[8], vv[8]; unp8(k4[qq], kv); unp8(v4[qq], vv);
      #pragma unroll
      for (int e=0;e<8;++e) kv[e] = __expf(kv[e]);
      *(float4*)&Kl[t*36 + qq*8]     = float4{kv[0],kv[1],kv[2],kv[3]};
      *(float4*)&Kl[t*36 + qq*8 + 4] = float4{kv[4],kv[5],kv[6],kv[7]};
      *(float4*)&Vl[t*36 + qq*8]     = float4{vv[0],vv[1],vv[2],vv[3]};
      *(float4*)&Vl[t*36 + qq*8 + 4] = float4{vv[4],vv[5],vv[6],vv[7]};
    }
    __syncthreads();
    for (int p = 0; p < 64; ++p){
      float4 kf = *(const float4*)&Kl[p*36 + ig*4];
      float4 vf = *(const float4*)&Vl[p*36 + og*4];
      float kfa[4] = {kf.x,kf.y,kf.z,kf.w};
      float vfa[4] = {vf.x,vf.y,vf.z,vf.w};
      #pragma unroll
      for (int i=0;i<4;++i){
        sacc[i] += kfa[i];
        #pragma unroll
        for (int j=0;j<4;++j) acc[i][j] = fmaf(kfa[i], vfa[j], acc[i][j]);
      }
    }
  }
  #pragma unroll
  for (int i=0;i<4;++i)
    #pragma unroll
    for (int j=0;j<4;++j)
      atomicAdd(&cl[(size_t)bp*1024 + (ig*4+i)*32 + og*4+j], acc[i][j]);
  if (og == 0){
    #pragma unroll
    for (int i=0;i<4;++i) atomicAdd(&S[bp*32 + ig*4 + i], sacc[i]);
  }
}

// ---------------- fused content(MFMA) + depthwise-5x5 + combine -> result NHWC ----------------
// Per block: one (16x16 px tile, head h, batch b). 4 waves, wave w owns rows w*4..w*4+3.
// content[px][o] = sum_i q[px][i] * clsT[o][i]  (clsT = cl^T * scale/S, bf16)
// via mfma(A=clsT frag, B=q frag): D[m=och][n=px].
__global__ __launch_bounds__(256) void content_combine(const u16* __restrict__ qkv,
    const float* __restrict__ cl, const float* __restrict__ S,
    const float* __restrict__ rel, u16* __restrict__ res){
  __shared__ u16 vt[12800];        // [hp=20*20][32ch], ch-grp(4) g at granule g^(hp&6)
  __shared__ u16 clsT[1024];       // [och][i] bf16, i-grp(8) at ((i>>3)^(och&3))<<3
  __shared__ float relT[800];      // [tap][och]
  const int t = threadIdx.x;
  const int tile = blockIdx.x, h = blockIdx.y, b = blockIdx.z;
  const int x0 = (tile&3)*16, y0 = (tile>>2)*16;
  const int bp = b*8 + h;
  const float scale = 0.17677669529663687f;
  #pragma unroll
  for (int it = 0; it < 4; ++it){
    int idx = t + 256*it;
    int och = idx & 31, i = idx >> 5;
    float val = cl[(size_t)bp*1024 + i*32 + och] * (scale / S[bp*32 + i]);
    clsT[och*32 + (((i>>3) ^ (och&3))<<3) + (i&7)] = f2bf(val);
  }
  for (int idx = t; idx < 800; idx += 256){
    int tap = idx>>5, ch = idx&31;
    relT[idx] = rel[ch*25 + tap];
  }
  // vt halo stage: 400 px x 4 uint4 (8 ch each) = 1600 granule-pairs
  #pragma unroll
  for (int i = 0; i < 7; ++i){
    int idx = t + 256*i;
    if (idx < 1600){
      int hp = idx>>2, gg = idx&3;          // gg: which 8-ch quarter (ch gg*8..+7)
      int hy = hp/20, hx = hp - hy*20;
      int y = y0 + hy - 2, x = x0 + hx - 2;
      uint4 v = uint4{0,0,0,0};
      if ((unsigned)y < 64u && (unsigned)x < 64u)
        v = *(const uint4*)&qkv[(size_t)(b*HW + y*64 + x)*768 + 512 + h*32 + gg*8];
      *(uint4*)&vt[hp*32 + (((gg*2) ^ (hp&6))<<2)] = v;
    }
  }
  __syncthreads();

  const int w = t>>6, lane = t&63;
  const int m15 = lane&15, q4 = lane>>4;
  // A-frags (clsT), loaded once
  bf16x8 af0 = __builtin_bit_cast(bf16x8, *(const uint4*)&clsT[m15*32 + ((q4 ^ (m15&3))<<3)]);
  bf16x8 af1 = __builtin_bit_cast(bf16x8, *(const uint4*)&clsT[(16+m15)*32 + ((q4 ^ ((16+m15)&3))<<3)]);
  // B-frags (q) + mfma, one per row
  f32x4 ca[4], cb[4];
  #pragma unroll
  for (int j = 0; j < 4; ++j){
    const int py = w*4 + j;
    const int pix = b*HW + (y0+py)*64 + x0 + m15;
    bf16x8 bq = __builtin_bit_cast(bf16x8,
        *(const uint4*)&qkv[(size_t)pix*768 + h*32 + q4*8]);
    ca[j] = __builtin_amdgcn_mfma_f32_16x16x32_bf16(af0, bq, f32x4{0.f,0.f,0.f,0.f}, 0,0,0);
    cb[j] = __builtin_amdgcn_mfma_f32_16x16x32_bf16(af1, bq, f32x4{0.f,0.f,0.f,0.f}, 0,0,0);
  }
  const int och4a = q4*4;          // lane's 4 consecutive och (tile0); tile1 = +16
  #pragma unroll
  for (int j = 0; j < 4; ++j){
    const int py = w*4 + j;
    const int pix = b*HW + (y0+py)*64 + x0 + m15;
    float pa[4] = {0.f,0.f,0.f,0.f}, pb[4] = {0.f,0.f,0.f,0.f};
    #pragma unroll
    for (int dy = 0; dy < 5; ++dy){
      const int rowb = (py+dy)*20 + m15;
      #pragma unroll
      for (int dx = 0; dx < 5; ++dx){
        const int hp = rowb + dx, m = hp&6;
        ushort4 va = *(const ushort4*)&vt[hp*32 + ((q4 ^ m)<<2)];
        ushort4 vb = *(const ushort4*)&vt[hp*32 + (((q4+4) ^ m)<<2)];
        float4 ra = *(const float4*)&relT[(dy*5+dx)*32 + och4a];
        float4 rb = *(const float4*)&relT[(dy*5+dx)*32 + och4a + 16];
        pa[0] = fmaf(ra.x, bf2f(va.x), pa[0]); pa[1] = fmaf(ra.y, bf2f(va.y), pa[1]);
        pa[2] = fmaf(ra.z, bf2f(va.z), pa[2]); pa[3] = fmaf(ra.w, bf2f(va.w), pa[3]);
        pb[0] = fmaf(rb.x, bf2f(vb.x), pb[0]); pb[1] = fmaf(rb.y, bf2f(vb.y), pb[1]);
        pb[2] = fmaf(rb.z, bf2f(vb.z), pb[2]); pb[3] = fmaf(rb.w, bf2f(vb.w), pb[3]);
      }
    }
    const u16* qp = qkv + (size_t)pix*768 + h*32;
    ushort4 qa = *(const ushort4*)&qp[och4a];
    ushort4 qb = *(const ushort4*)&qp[och4a + 16];
    ushort4 sa, sb;
    sa.x = f2bf(ca[j][0] + bf2f(qa.x)*pa[0]);
    sa.y = f2bf(ca[j][1] + bf2f(qa.y)*pa[1]);
    sa.z = f2bf(ca[j][2] + bf2f(qa.z)*pa[2]);
    sa.w = f2bf(ca[j][3] + bf2f(qa.w)*pa[3]);
    sb.x = f2bf(cb[j][0] + bf2f(qb.x)*pb[0]);
    sb.y = f2bf(cb[j][1] + bf2f(qb.y)*pb[1]);
    sb.z = f2bf(cb[j][2] + bf2f(qb.z)*pb[2]);
    sb.w = f2bf(cb[j][3] + bf2f(qb.w)*pb[3]);
    u16* rp = res + (size_t)pix*256 + h*32;
    *(ushort4*)&rp[och4a]      = sa;
    *(ushort4*)&rp[och4a + 16] = sb;
  }
}

extern "C" void kernel_launch(void* const* d_in, const int* in_sizes, int n_in,
                              void* d_out, int out_size, void* d_ws, size_t ws_size,
                              hipStream_t stream) {
  const float* src   = (const float*)d_in[0];
  const float* rel   = (const float*)d_in[1];
  const float* qkv_w = (const float*)d_in[2];
  const float* cpe_w = (const float*)d_in[3];
  const float* cpe_b = (const float*)d_in[4];
  const float* out_w = (const float*)d_in[5];
  const float* out_b = (const float*)d_in[6];
  char* ws = (char*)d_ws;
  u16*   qkv  = (u16*)(ws);
  u16*   xpad = (u16*)(ws);                    // aliased (dead after conv)
  u16*   xbuf = (u16*)(ws + 100663296);
  float* cl   = (float*)(ws + 134217728);
  float* S    = (float*)(ws + 134742016);
  u16*   wrb  = (u16*)(ws + 134758400);
  u16*   wq   = (u16*)(ws + 135938048);
  u16*   wo   = (u16*)(ws + 136331264);

  zero_border<<<dim3(520), dim3(256), 0, stream>>>(xpad);
  to_nhwc<<<dim3(64, 16), dim3(256), 0, stream>>>(src, xpad);
  repack_w<<<dim3(3328), dim3(256), 0, stream>>>(cpe_w, qkv_w, out_w, wrb, wq, wo);
  conv_mfma<<<dim3(1024), dim3(256), 0, stream>>>(xpad, wrb, cpe_b, xbuf);
  gemm_mfma<768,6,false><<<dim3(3072), dim3(256), 0, stream>>>(xbuf, wq, nullptr, (void*)qkv);
  zero_cl<<<dim3(528), dim3(256), 0, stream>>>(cl);
  lambda_kern<<<dim3(128, 16), dim3(64), 0, stream>>>(qkv, cl, S);
  content_combine<<<dim3(16, 8, 16), dim3(256), 0, stream>>>(qkv, cl, S, rel, xbuf);
  gemm_mfma<256,2,true><<<dim3(1024), dim3(256), 0, stream>>>(xbuf, wo, out_b, d_out);
}